// Round 3
// baseline (238.865 us; speedup 1.0000x reference)
//
#include <hip/hip_runtime.h>

// Problem constants
#define B 8
#define S 4096
#define H 32
#define D 128
#define DM 4096   // H*D

#define CS 64             // s-rows per chunk
#define NCHUNK (S / CS)   // 64 chunks -> 512 blocks
#define NT 1024
#define PSTR 132          // partial record stride (floats): 128 O + m + l (+pad)

// ---------------------------------------------------------------------------
// Kernel 1: q = hidden @ Wq^T + bq.  One wave per output column j (all 8
// batches). Wq rows read exactly once, coalesced float4; hidden L1-resident.
// ---------------------------------------------------------------------------
__global__ __launch_bounds__(256) void qproj_kernel(
    const float* __restrict__ hidden, const float* __restrict__ Wq,
    const float* __restrict__ bq, float* __restrict__ qout)
{
    const int lane = threadIdx.x & 63;
    const int wave = threadIdx.x >> 6;
    const int j = blockIdx.x * 4 + wave;

    const float4* __restrict__ w   = (const float4*)(Wq + (size_t)j * DM);
    const float4* __restrict__ hid = (const float4*)hidden;

    float a[B];
#pragma unroll
    for (int b = 0; b < B; ++b) a[b] = 0.f;

#pragma unroll 4
    for (int i = 0; i < DM / (4 * 64); ++i) {   // 16 iterations
        const int idx = lane + 64 * i;
        const float4 wv = w[idx];
#pragma unroll
        for (int b = 0; b < B; ++b) {
            const float4 hv = hid[b * (DM / 4) + idx];
            a[b] += wv.x * hv.x + wv.y * hv.y + wv.z * hv.z + wv.w * hv.w;
        }
    }
#pragma unroll
    for (int b = 0; b < B; ++b) {
#pragma unroll
        for (int mk = 1; mk <= 32; mk <<= 1) a[b] += __shfl_xor(a[b], mk);
    }
    if (lane == 0) {
        const float bias = bq[j];
#pragma unroll
        for (int b = 0; b < B; ++b) qout[b * DM + j] = a[b] + bias;
    }
}

// ---------------------------------------------------------------------------
// Kernel 2: flash-decode partial, contiguous-stream layout.
// One block per (b, s-chunk of 64 rows), ALL 32 heads. 1024 threads:
// thread tid owns elements [4*tid, 4*tid+4) of every 16 KB row, so the
// block reads K (then V) as a single linear 1 MB stream. 32-lane gang
// g = tid>>5 is exactly head g. No __syncthreads anywhere (gang-local data;
// 2 gangs per wave, LDS RAW within a wave is ordered).
// ---------------------------------------------------------------------------
__global__ __launch_bounds__(NT, 8) void attn_partial(
    const float* __restrict__ kptr, const float* __restrict__ vptr,
    const float* __restrict__ qws, float* __restrict__ part)
{
    __shared__ float sc[H][CS + 1];     // +1 pad; 8.3 KB

    const int tid = threadIdx.x;
    const int g   = tid >> 5;           // head 0..31
    const int l   = tid & 31;
    const int c   = blockIdx.x & (NCHUNK - 1);
    const int b   = blockIdx.x >> 6;    // NCHUNK = 64

    // K[b, c*CS, 0, 0] — block streams CS*DM floats linearly from here
    const size_t base = ((size_t)b * S + (size_t)c * CS) * DM;
    const float4* __restrict__ kb = (const float4*)(kptr + base);
    const float4* __restrict__ vb = (const float4*)(vptr + base);

    const float4 q4 = *(const float4*)(qws + (size_t)b * DM + 4 * tid);

    // ---- Phase 1: scores (one full 16 KB row per iteration, coalesced) ----
#pragma unroll 4
    for (int s = 0; s < CS; ++s) {
        const float4 k4 = kb[(size_t)s * (DM / 4) + tid];
        float p = q4.x * k4.x + q4.y * k4.y + q4.z * k4.z + q4.w * k4.w;
        p += __shfl_xor(p, 1);
        p += __shfl_xor(p, 2);
        p += __shfl_xor(p, 4);
        p += __shfl_xor(p, 8);
        p += __shfl_xor(p, 16);
        if (l == 0) sc[g][s] = p;
    }

    // ---- gang-local softmax over the chunk (64 scores per head) ----
    const float s0v = sc[g][l];
    const float s1v = sc[g][l + 32];
    float m = fmaxf(s0v, s1v);
#pragma unroll
    for (int mk = 1; mk <= 16; mk <<= 1) m = fmaxf(m, __shfl_xor(m, mk));
    const float e0 = __expf(s0v - m);
    const float e1 = __expf(s1v - m);
    float sum = e0 + e1;
#pragma unroll
    for (int mk = 1; mk <= 16; mk <<= 1) sum += __shfl_xor(sum, mk);
    sc[g][l]      = e0;
    sc[g][l + 32] = e1;

    // ---- Phase 2: partial O = exp(S) @ V (linear V stream) ----
    float4 acc = make_float4(0.f, 0.f, 0.f, 0.f);
#pragma unroll 4
    for (int s = 0; s < CS; ++s) {
        const float p = sc[g][s];       // broadcast within gang
        const float4 v4 = vb[(size_t)s * (DM / 4) + tid];
        acc.x += p * v4.x;
        acc.y += p * v4.y;
        acc.z += p * v4.z;
        acc.w += p * v4.w;
    }

    // ---- write partial record for (b, head g, chunk c) ----
    float* rec = part + ((size_t)(b * H + g) * NCHUNK + c) * PSTR;
    *(float4*)(rec + 4 * l) = acc;
    if (l == 0) { rec[D] = m; rec[D + 1] = sum; }
}

// ---------------------------------------------------------------------------
// Kernel 3: merge the NCHUNK partials per (b,h).
// ---------------------------------------------------------------------------
__global__ __launch_bounds__(128) void combine_kernel(
    const float* __restrict__ part, float* __restrict__ out)
{
    const int bh = blockIdx.x;          // 0..255
    const int d  = threadIdx.x;         // 0..127
    const float* rec = part + (size_t)bh * NCHUNK * PSTR;

    float M = -3.4e38f;
#pragma unroll 8
    for (int c = 0; c < NCHUNK; ++c) M = fmaxf(M, rec[c * PSTR + D]);
    float denom = 0.f, o = 0.f;
#pragma unroll 8
    for (int c = 0; c < NCHUNK; ++c) {
        const float w = __expf(rec[c * PSTR + D] - M);
        denom += w * rec[c * PSTR + D + 1];
        o     += w * rec[c * PSTR + d];
    }
    out[(size_t)bh * D + d] = o / denom;
}

extern "C" void kernel_launch(void* const* d_in, const int* in_sizes, int n_in,
                              void* d_out, int out_size, void* d_ws, size_t ws_size,
                              hipStream_t stream)
{
    const float* hidden = (const float*)d_in[0];
    const float* keys   = (const float*)d_in[1];
    const float* vals   = (const float*)d_in[2];
    const float* Wq     = (const float*)d_in[3];
    const float* bq     = (const float*)d_in[4];
    float* outp = (float*)d_out;
    float* qws  = (float*)d_ws;                   // B*DM floats = 128 KB
    float* part = qws + (size_t)B * DM;           // 256*64*132 floats ≈ 8.7 MB

    qproj_kernel<<<DM / 4, 256, 0, stream>>>(hidden, Wq, bq, qws);
    attn_partial<<<B * NCHUNK, NT, 0, stream>>>(keys, vals, qws, part);
    combine_kernel<<<B * H, 128, 0, stream>>>(part, outp);
}